// Round 6
// baseline (196.615 us; speedup 1.0000x reference)
//
#include <hip/hip_runtime.h>

typedef unsigned short u16;
typedef unsigned int u32;
typedef __attribute__((ext_vector_type(8))) short bf16x8;
typedef __attribute__((ext_vector_type(4))) float f32x4;

__device__ __forceinline__ u16 f2bf(float f) {
    u32 u = __float_as_uint(f);
    u += 0x7fffu + ((u >> 16) & 1u);
    return (u16)(u >> 16);
}

// async global->LDS DMA, 16B per lane, LDS dest = wave-uniform base + lane*16
#define GL2LDS(gp, lp)                                                                 \
    __builtin_amdgcn_global_load_lds((const __attribute__((address_space(1))) u32*)(const void*)(gp), \
                                     (__attribute__((address_space(3))) u32*)(void*)(lp), 16, 0, 0)

// ---------------- cast fp32 -> bf16 (vectorized x4) ----------------
__global__ __launch_bounds__(256) void cast_kernel(const float* __restrict__ src,
                                                   u16* __restrict__ dst, int n4) {
    int i = blockIdx.x * 256 + threadIdx.x;
    if (i >= n4) return;
    float4 val = ((const float4*)src)[i];
    uint2 o;
    o.x = ((u32)f2bf(val.y) << 16) | f2bf(val.x);
    o.y = ((u32)f2bf(val.w) << 16) | f2bf(val.z);
    ((uint2*)dst)[i] = o;
}

// ---------------- transpose+cast all 4 weight matrices in one launch ----------------
__global__ __launch_bounds__(256) void transpose4(const float* __restrict__ Wq,
                                                  const float* __restrict__ Wk,
                                                  const float* __restrict__ Wv,
                                                  const float* __restrict__ Wo,
                                                  u16* __restrict__ Wcat,
                                                  u16* __restrict__ Wot) {
    __shared__ float tl[32][33];
    const int zi = blockIdx.z;
    const float* src = (zi == 0) ? Wq : (zi == 1) ? Wk : (zi == 2) ? Wv : Wo;
    u16* dst = (zi < 3) ? (Wcat + zi * 1048576) : Wot;
    const int tx = threadIdx.x & 31, ty = threadIdx.x >> 5;
    const int kt = blockIdx.y * 32, nt = blockIdx.x * 32;
#pragma unroll
    for (int j = 0; j < 4; ++j)
        tl[ty + j * 8][tx] = src[(kt + ty + j * 8) * 1024 + nt + tx];
    __syncthreads();
#pragma unroll
    for (int j = 0; j < 4; ++j)
        dst[(nt + ty + j * 8) * 1024 + kt + tx] = f2bf(tl[tx][ty + j * 8]);
}

// R_hat table: tab[h][dist] = (1+e^v)/(1+e^(v-w*dist))/sqrt(64) * log2(e)  (exp2-baked);
// also zeroes job counter.
__global__ __launch_bounds__(256) void rtab_kernel(const float* __restrict__ wp,
                                                   const float* __restrict__ vp,
                                                   float* __restrict__ tab,
                                                   u32* __restrict__ counter) {
    const int i = blockIdx.x * 256 + threadIdx.x;  // 16*2048
    if (i == 0) counter[0] = 0u;                   // work-stealing counter for attn
    const int h = i >> 11, d = i & 2047;
    const float vv = vp[h], ww = wp[h];
    tab[i] = (1.f + expf(vv)) / (1.f + expf(vv - ww * (float)d)) *
             (0.125f * 1.44269504088896340736f);
}

// ---------------- m97-style bf16 MFMA GEMM: 128xBN tile, BK=64, global_load_lds ------
// C = A[M][K] @ Bt[N][K]^T.  LDS tiles unpadded, XOR-swizzled (chunk ^= row&7).
// MODE 0: fp32 out + bias.
// MODE 1: col<2048 -> Cb bf16 [M][2048] (Q|K); col>=2048 -> Vt bf16 [1024][4096] (V^T,
//         with seq order inside each 64-block PERMUTED so attn PV A-frags are one b128:
//         seq = 32a+16b+4c+d  ->  pos = (4a+c)*8 + 4b + d).  [verified R2: conflicts 0]
template <int MODE, int BN>
__global__ __launch_bounds__(256, 3) void gemm128(const u16* __restrict__ A,
                                                  const u16* __restrict__ Bt,
                                                  float* __restrict__ C,
                                                  const float* __restrict__ bias,
                                                  u16* __restrict__ Cb,
                                                  u16* __restrict__ Vt,
                                                  int M, int N, int K) {
    constexpr int NBW = BN / 32;  // 16-wide n-blocks per wave
    __shared__ __align__(16) u16 As[8192];      // 128 rows x 64
    __shared__ __align__(16) u16 Bs[BN * 64];   // BN rows x 64
    const int t = threadIdx.x, lane = t & 63, wv = t >> 6;
    const int l15 = lane & 15, quad = lane >> 4;
    const int m0 = blockIdx.y << 7, n0 = blockIdx.x * BN;
    const int wm = (wv & 1) << 6, wn = (wv >> 1) * (BN / 2);

    f32x4 acc[4][NBW];
#pragma unroll
    for (int i = 0; i < 4; ++i)
#pragma unroll
        for (int j = 0; j < NBW; ++j) acc[i][j] = (f32x4){0.f, 0.f, 0.f, 0.f};

    const int lrow = lane >> 3, lchunk = lane & 7;
    for (int k0 = 0; k0 < K; k0 += 64) {
#pragma unroll
        for (int c = 0; c < 4; ++c) {  // A: 128 rows
            const int r0 = wv * 32 + c * 8;
            const int row = r0 + lrow;
            const int g = lchunk ^ (row & 7);
            GL2LDS(A + (size_t)(m0 + row) * K + k0 + g * 8, &As[r0 * 64]);
        }
#pragma unroll
        for (int c = 0; c < BN / 32; ++c) {  // B: BN rows
            const int r0 = wv * (BN / 4) + c * 8;
            const int row = r0 + lrow;
            const int g = lchunk ^ (row & 7);
            GL2LDS(Bt + (size_t)(n0 + row) * K + k0 + g * 8, &Bs[r0 * 64]);
        }
        __syncthreads();  // drains global_load_lds (vmcnt) + protects prior reads
#pragma unroll
        for (int ks = 0; ks < 2; ++ks) {
            const int p = ((ks << 2) | quad) ^ (l15 & 7);
            bf16x8 af[4], bfr[NBW];
#pragma unroll
            for (int i = 0; i < 4; ++i)
                af[i] = *(const bf16x8*)&As[(wm + i * 16 + l15) * 64 + p * 8];
#pragma unroll
            for (int j = 0; j < NBW; ++j)
                bfr[j] = *(const bf16x8*)&Bs[(wn + j * 16 + l15) * 64 + p * 8];
#pragma unroll
            for (int mb = 0; mb < 4; ++mb)
#pragma unroll
                for (int nb = 0; nb < NBW; ++nb)
                    acc[mb][nb] = __builtin_amdgcn_mfma_f32_16x16x32_bf16(af[mb], bfr[nb],
                                                                          acc[mb][nb], 0, 0, 0);
        }
        __syncthreads();  // protect LDS before next stage overwrites
    }
    // epilogue: C/D layout col=lane&15, row=(lane>>4)*4+reg
    const int rb = m0 + wm + (quad << 2);
    const int cbase = n0 + wn + l15;
#pragma unroll
    for (int mb = 0; mb < 4; ++mb)
#pragma unroll
        for (int nb = 0; nb < NBW; ++nb) {
            const int col = cbase + nb * 16;
            if (MODE == 0) {
#pragma unroll
                for (int r = 0; r < 4; ++r) {
                    const int row = rb + mb * 16 + r;
                    C[(size_t)row * N + col] = acc[mb][nb][r] + bias[col];
                }
            } else if (col < 2048) {  // Q|K: row-major bf16 [M][2048]
#pragma unroll
                for (int r = 0; r < 4; ++r) {
                    const int row = rb + mb * 16 + r;
                    Cb[(size_t)row * 2048 + col] = f2bf(acc[mb][nb][r]);
                }
            } else {  // V: permuted V^T store; lane's 4 seq rows are 4 consecutive pos
                      // seq6 = quad*4 + mb*16 + r -> a=mb>>1, b=mb&1, c=quad, d=r
                const int pos = (((mb >> 1) * 4 + quad) << 3) + ((mb & 1) << 2);
                uint2 o;
                o.x = (u32)f2bf(acc[mb][nb][0]) | ((u32)f2bf(acc[mb][nb][1]) << 16);
                o.y = (u32)f2bf(acc[mb][nb][2]) | ((u32)f2bf(acc[mb][nb][3]) << 16);
                *(uint2*)(Vt + (size_t)(col - 2048) * 4096 + (m0 + wm) + pos) = o;
            }
        }
}

// ---------------- MFMA flash attention v10: 128-q jobs, 8-wave blocks ----------------
// Per-wave inner loop is byte-identical to the proven R3/R5 kernel (VGPR ~76, no
// spills); the change is amortization: one K/V staging round (16 KB) now serves 128 q
// rows (8 waves x 16 q) instead of 64 -> barriers, staging traffic, rall fills, and
// job overhead all halve per unit of work. Causal: wave-uniform masked branch when
// kt >= 2j + (wv>>2); lower-half waves run one fully-masked tile per job (~3% waste).
// Staging role split: waves 0-3 stage K (2 GL2LDS each), waves 4-7 stage V.
// 512 jobs (j=q-double-tile, bh), grid 448, longest-first stealing: the 448 initial
// claims are exactly the 14 longest job levels; the 64 short (2-4 iter) jobs get
// stolen by early finishers (LPT balance).
__global__ __launch_bounds__(512, 2) void attn_kernel(const u16* __restrict__ qkb,
                                                      const u16* __restrict__ vtb,
                                                      const float* __restrict__ rtab,
                                                      u16* __restrict__ ctxb,
                                                      u32* __restrict__ counter) {
    __shared__ __align__(16) u16 Kt[2][4096];   // [kseq][d] swizzled, 8KB x2
    __shared__ __align__(16) u16 Vt2[2][4096];  // [d][kseq-permuted] swizzled, 8KB x2
    __shared__ __align__(16) float rall[2048];  // R_hat*log2e/8 row for this head
    __shared__ int jobS;

    const int t = threadIdx.x, lane = t & 63, wv = t >> 6;   // wv 0..7
    const int l15 = lane & 15, quad = lane >> 4;
    const int lrow = lane >> 3, lchunk = lane & 7;
    const int sr0 = (wv & 3) * 16;   // staging row base for this wave's role

    for (;;) {
        if (t == 0) jobS = (int)atomicAdd(counter, 1u);
        __syncthreads();       // jobS visible; fences prior job's LDS reads
        const int job = jobS;
        if (job >= 512) break;
        const int j = 15 - (job >> 5);        // longest jobs first (32 iters .. 2)
        const int bh = job & 31;
        const int b = bh >> 4, h = bh & 15;
        const int q0 = j << 7;                // 128-q double tile
        const int ktmax = 2 * j + 1;

        // rall fill, vectorized f32x4 (q0+128 is a multiple of 128 -> exact)
        {
            const float4* src = (const float4*)(rtab + (h << 11));
            const int nf = (q0 + 128) >> 2;
            for (int i = t; i < nf; i += 512) ((float4*)rall)[i] = src[i];
        }

        // Q as B-operand fragments for S^T: lane n=l15 -> q = q0+wv*16+l15, k=d
        bf16x8 qb[2];
        {
            const u16* qrow = qkb + (size_t)(b * 2048 + q0 + (wv << 4) + l15) * 2048 +
                              (h << 6) + quad * 8;
            qb[0] = *(const bf16x8*)(qrow);
            qb[1] = *(const bf16x8*)(qrow + 32);
        }

        f32x4 cacc[4];   // ctx^T accum: db d-blocks, lane holds (d=quad*4+r, q=l15)
#pragma unroll
        for (int i = 0; i < 4; ++i) cacc[i] = (f32x4){0.f, 0.f, 0.f, 0.f};
        f32x4 lacc4 = (f32x4){0.f, 0.f, 0.f, 0.f};  // 4-chain softmax denom partials

        // stage kt=0 into buffer 0 (waves 0-3: K rows sr0..sr0+15; waves 4-7: V^T)
#pragma unroll
        for (int c = 0; c < 2; ++c) {
            const int r0 = sr0 + c * 8;
            const int row = r0 + lrow;
            const int g = lchunk ^ (row & 7);
            if (wv < 4)
                GL2LDS(qkb + (size_t)(b * 2048 + row) * 2048 + 1024 + (h << 6) + g * 8,
                       &Kt[0][r0 * 64]);
            else
                GL2LDS(vtb + (size_t)((h << 6) + row) * 4096 + b * 2048 + g * 8,
                       &Vt2[0][r0 * 64]);
        }

        for (int kt = 0; kt <= ktmax; ++kt) {
            const int bsel = kt & 1;
            __syncthreads();  // drains staging of buf[bsel] (vmcnt) + orders LDS reuse
            if (kt < ktmax) {  // prefetch kt+1 into other buffer
                const int kg0 = (kt + 1) << 6;
#pragma unroll
                for (int c = 0; c < 2; ++c) {
                    const int r0 = sr0 + c * 8;
                    const int row = r0 + lrow;
                    const int g = lchunk ^ (row & 7);
                    if (wv < 4)
                        GL2LDS(qkb + (size_t)(b * 2048 + kg0 + row) * 2048 + 1024 + (h << 6) + g * 8,
                               &Kt[bsel ^ 1][r0 * 64]);
                    else
                        GL2LDS(vtb + (size_t)((h << 6) + row) * 4096 + b * 2048 + kg0 + g * 8,
                               &Vt2[bsel ^ 1][r0 * 64]);
                }
            }

            // ---- S^T = K @ Q^T : 64 kseq x 16 q per wave (8 MFMA), A=K from LDS ----
            f32x4 sacc[4];
#pragma unroll
            for (int i = 0; i < 4; ++i) sacc[i] = (f32x4){0.f, 0.f, 0.f, 0.f};
            __builtin_amdgcn_s_setprio(1);
#pragma unroll
            for (int ks = 0; ks < 2; ++ks) {
                const int p = ((ks << 2) | quad) ^ (l15 & 7);
#pragma unroll
                for (int mb = 0; mb < 4; ++mb) {
                    bf16x8 ka = *(const bf16x8*)&Kt[bsel][(mb * 16 + l15) * 64 + p * 8];
                    sacc[mb] = __builtin_amdgcn_mfma_f32_16x16x32_bf16(ka, qb[ks],
                                                                       sacc[mb], 0, 0, 0);
                }
            }
            __builtin_amdgcn_s_setprio(0);

            // ---- gate + exp2 (fixed m=0), 4-chain l accum, pack P to bf16 regs ----
            // lane value (mb,r): q = q0+wv*16+l15, kseq = kg0+mb*16+quad*4+r
            const int D0 = q0 - (kt << 6) + (wv << 4) + l15;  // q - kg0 - local kseq base
            u32 pk[4][2];
            if (kt < 2 * j + (wv >> 2)) {  // off-diagonal for this wave: dist >= 1
#pragma unroll
                for (int mb = 0; mb < 4; ++mb) {
                    float pe[4];
#pragma unroll
                    for (int r = 0; r < 4; ++r) {
                        const int dist = D0 - (mb * 16 + (quad << 2) + r);
                        pe[r] = exp2f(fmaxf(sacc[mb][r], 0.f) * rall[dist]);
                        lacc4[r] += pe[r];
                    }
                    pk[mb][0] = (__float_as_uint(pe[0]) >> 16) |
                                (__float_as_uint(pe[1]) & 0xffff0000u);
                    pk[mb][1] = (__float_as_uint(pe[2]) >> 16) |
                                (__float_as_uint(pe[3]) & 0xffff0000u);
                }
            } else {  // diagonal / fully-masked tile: causal mask (dist<0 -> 0)
#pragma unroll
                for (int mb = 0; mb < 4; ++mb) {
                    float pe[4];
#pragma unroll
                    for (int r = 0; r < 4; ++r) {
                        const int dist = D0 - (mb * 16 + (quad << 2) + r);
                        const int di = dist < 0 ? 0 : dist;
                        float p0 = exp2f(fmaxf(sacc[mb][r], 0.f) * rall[di]);
                        pe[r] = (dist < 0) ? 0.f : p0;
                        lacc4[r] += pe[r];
                    }
                    pk[mb][0] = (__float_as_uint(pe[0]) >> 16) |
                                (__float_as_uint(pe[1]) & 0xffff0000u);
                    pk[mb][1] = (__float_as_uint(pe[2]) >> 16) |
                                (__float_as_uint(pe[3]) & 0xffff0000u);
                }
            }

            // ---- ctx^T += V^T @ P^T : 8 MFMA, B-frag = own packed P regs ----
            // permuted Vt2: A-frag for (ks,db) is ONE b128 at chunk (4ks+quad)^swz
            __builtin_amdgcn_s_setprio(1);
#pragma unroll
            for (int ks = 0; ks < 2; ++ks) {
                int4 pv = {(int)pk[2 * ks][0], (int)pk[2 * ks][1],
                           (int)pk[2 * ks + 1][0], (int)pk[2 * ks + 1][1]};
                bf16x8 pb = *(bf16x8*)&pv;
                const int g = (4 * ks + quad) ^ (l15 & 7);
#pragma unroll
                for (int db = 0; db < 4; ++db) {
                    bf16x8 vf = *(const bf16x8*)&Vt2[bsel][(db * 16 + l15) * 64 + g * 8];
                    cacc[db] = __builtin_amdgcn_mfma_f32_16x16x32_bf16(vf, pb,
                                                                       cacc[db], 0, 0, 0);
                }
            }
            __builtin_amdgcn_s_setprio(0);
        }

        // ---- epilogue: l = quad-column reduce; normalize; store ctx (8B/store) ----
        float lt = (lacc4[0] + lacc4[1]) + (lacc4[2] + lacc4[3]);
        lt += __shfl_xor(lt, 16, 64);
        lt += __shfl_xor(lt, 32, 64);
        const float inv = 1.f / lt;
        u16* op = ctxb + (size_t)(b * 2048 + q0 + (wv << 4) + l15) * 1024 +
                  (h << 6) + (quad << 2);
#pragma unroll
        for (int db = 0; db < 4; ++db) {
            uint2 o;
            o.x = (u32)f2bf(cacc[db][0] * inv) | ((u32)f2bf(cacc[db][1] * inv) << 16);
            o.y = (u32)f2bf(cacc[db][2] * inv) | ((u32)f2bf(cacc[db][3] * inv) << 16);
            *(uint2*)(op + db * 16) = o;
        }
        // loop-top __syncthreads() fences these LDS reads before next job's writes
    }
}

extern "C" void kernel_launch(void* const* d_in, const int* in_sizes, int n_in,
                              void* d_out, int out_size, void* d_ws, size_t ws_size,
                              hipStream_t stream) {
    const float* x  = (const float*)d_in[0];
    const float* Wq = (const float*)d_in[1];
    const float* Wk = (const float*)d_in[2];
    const float* Wv = (const float*)d_in[3];
    const float* Wo = (const float*)d_in[4];
    const float* bo = (const float*)d_in[5];
    const float* w  = (const float*)d_in[6];
    const float* v  = (const float*)d_in[7];
    float* out = (float*)d_out;

    char* w8 = (char*)d_ws;
    u16*  xb   = (u16*)(w8);                     //  8 MB : x bf16 [4096][1024]
    u16*  Wcat = (u16*)(w8 + (8u << 20));        //  6 MB : (Wq|Wk|Wv)^T bf16 [3072][1024]
    u16*  Wot  = (u16*)(w8 + (14u << 20));       //  2 MB : Wo^T bf16 [1024][1024]
    u16*  qkb  = (u16*)(w8 + (16u << 20));       // 16 MB : Q|K bf16 [4096][2048]
    u16*  vtb  = (u16*)(w8 + (32u << 20));       //  8 MB : V^T bf16 [1024][4096] (permuted)
    u16*  ctxb = (u16*)(w8 + (40u << 20));       //  8 MB : ctx bf16 [4096][1024]
    float* rtab = (float*)(w8 + (48u << 20));    // 128 KB: R_hat*log2e/8 [16][2048]
    u32*  counter = (u32*)(w8 + (48u << 20) + (1u << 17));  // 4 B : job counter

    cast_kernel<<<4096, 256, 0, stream>>>(x, xb, 1048576);
    transpose4<<<dim3(32, 32, 4), 256, 0, stream>>>(Wq, Wk, Wv, Wo, Wcat, Wot);
    rtab_kernel<<<128, 256, 0, stream>>>(w, v, rtab, counter);

    // QKV fused projection -> bf16 qkb (Q|K) + V^T direct (permuted)  [M=4096, N=3072, K=1024]
    gemm128<1, 128><<<dim3(24, 32), 256, 0, stream>>>(xb, Wcat, nullptr, nullptr, qkb, vtb,
                                                      4096, 3072, 1024);
    // MFMA flash attention: 448 persistent 8-wave blocks, 512 jobs, work-stealing
    attn_kernel<<<448, 512, 0, stream>>>(qkb, vtb, rtab, ctxb, counter);
    // output projection + bias (fp32 out)   [M=4096, N=1024, K=1024], 128x64 tiles
    gemm128<0, 64><<<dim3(16, 32), 256, 0, stream>>>(ctxb, Wot, out, bo, nullptr, nullptr,
                                                     4096, 1024, 1024);
}

// Round 7
// 185.986 us; speedup vs baseline: 1.0572x; 1.0572x over previous
//
#include <hip/hip_runtime.h>

typedef unsigned short u16;
typedef unsigned int u32;
typedef __attribute__((ext_vector_type(8))) short bf16x8;
typedef __attribute__((ext_vector_type(4))) float f32x4;

__device__ __forceinline__ u16 f2bf(float f) {
    u32 u = __float_as_uint(f);
    u += 0x7fffu + ((u >> 16) & 1u);
    return (u16)(u >> 16);
}

// pack two f32 -> one u32 of two bf16 (RNE), 1 VALU inst (vs 3 for shift/and/or)
__device__ __forceinline__ u32 cvtpk(float lo, float hi) {
    u32 r;
    asm("v_cvt_pk_bf16_f32 %0, %1, %2" : "=v"(r) : "v"(lo), "v"(hi));
    return r;
}

// async global->LDS DMA, 16B per lane, LDS dest = wave-uniform base + lane*16
#define GL2LDS(gp, lp)                                                                 \
    __builtin_amdgcn_global_load_lds((const __attribute__((address_space(1))) u32*)(const void*)(gp), \
                                     (__attribute__((address_space(3))) u32*)(void*)(lp), 16, 0, 0)

// ------------- fused prep: cast x (bid<4096) | transpose W (bid<8192) | rtab -------------
__global__ __launch_bounds__(256) void prep_kernel(const float* __restrict__ x,
                                                   const float* __restrict__ Wq,
                                                   const float* __restrict__ Wk,
                                                   const float* __restrict__ Wv,
                                                   const float* __restrict__ Wo,
                                                   const float* __restrict__ wp,
                                                   const float* __restrict__ vp,
                                                   u16* __restrict__ xb,
                                                   u16* __restrict__ Wcat,
                                                   u16* __restrict__ Wot,
                                                   float* __restrict__ tab,
                                                   u32* __restrict__ counter) {
    __shared__ float tl[32][33];
    const int bid = blockIdx.x, t = threadIdx.x;
    if (bid < 4096) {  // ---- cast x fp32 -> bf16, float4/thread ----
        const int i = bid * 256 + t;
        float4 val = ((const float4*)x)[i];
        uint2 o;
        o.x = cvtpk(val.x, val.y);
        o.y = cvtpk(val.z, val.w);
        ((uint2*)xb)[i] = o;
    } else if (bid < 8192) {  // ---- transpose+cast one 32x32 tile of Wq/Wk/Wv/Wo ----
        const int tid = bid - 4096;
        const int zi = tid >> 10, rem = tid & 1023;
        const int kt = (rem >> 5) * 32, nt = (rem & 31) * 32;
        const float* src = (zi == 0) ? Wq : (zi == 1) ? Wk : (zi == 2) ? Wv : Wo;
        u16* dst = (zi < 3) ? (Wcat + zi * 1048576) : Wot;
        const int tx = t & 31, ty = t >> 5;
#pragma unroll
        for (int j = 0; j < 4; ++j)
            tl[ty + j * 8][tx] = src[(kt + ty + j * 8) * 1024 + nt + tx];
        __syncthreads();
#pragma unroll
        for (int j = 0; j < 4; ++j)
            dst[(nt + ty + j * 8) * 1024 + kt + tx] = f2bf(tl[tx][ty + j * 8]);
    } else {  // ---- R_hat table: (1+e^v)/(1+e^(v-w*d))/8 * log2e (exp2-baked) ----
        const int i = (bid - 8192) * 256 + t;  // 16*2048
        if (i == 0) counter[0] = 0u;           // work-stealing counter for attn
        const int h = i >> 11, d = i & 2047;
        const float vv = vp[h], ww = wp[h];
        tab[i] = (1.f + expf(vv)) / (1.f + expf(vv - ww * (float)d)) *
                 (0.125f * 1.44269504088896340736f);
    }
}

// ---------------- m97-style bf16 MFMA GEMM: 128xBN tile, BK=64, global_load_lds ------
// C = A[M][K] @ Bt[N][K]^T.  LDS tiles unpadded, XOR-swizzled (chunk ^= row&7).
// MODE 0: fp32 out + bias.
// MODE 1: col<2048 -> Cb bf16 [M][2048] (Q|K); col>=2048 -> Vt bf16 [1024][4096] (V^T,
//         with seq order inside each 64-block PERMUTED so attn PV A-frags are one b128:
//         seq = 32a+16b+4c+d  ->  pos = (4a+c)*8 + 4b + d).  [verified R2: conflicts 0]
template <int MODE, int BN>
__global__ __launch_bounds__(256, 3) void gemm128(const u16* __restrict__ A,
                                                  const u16* __restrict__ Bt,
                                                  float* __restrict__ C,
                                                  const float* __restrict__ bias,
                                                  u16* __restrict__ Cb,
                                                  u16* __restrict__ Vt,
                                                  int M, int N, int K) {
    constexpr int NBW = BN / 32;  // 16-wide n-blocks per wave
    __shared__ __align__(16) u16 As[8192];      // 128 rows x 64
    __shared__ __align__(16) u16 Bs[BN * 64];   // BN rows x 64
    const int t = threadIdx.x, lane = t & 63, wv = t >> 6;
    const int l15 = lane & 15, quad = lane >> 4;
    const int m0 = blockIdx.y << 7, n0 = blockIdx.x * BN;
    const int wm = (wv & 1) << 6, wn = (wv >> 1) * (BN / 2);

    f32x4 acc[4][NBW];
#pragma unroll
    for (int i = 0; i < 4; ++i)
#pragma unroll
        for (int j = 0; j < NBW; ++j) acc[i][j] = (f32x4){0.f, 0.f, 0.f, 0.f};

    const int lrow = lane >> 3, lchunk = lane & 7;
    for (int k0 = 0; k0 < K; k0 += 64) {
#pragma unroll
        for (int c = 0; c < 4; ++c) {  // A: 128 rows
            const int r0 = wv * 32 + c * 8;
            const int row = r0 + lrow;
            const int g = lchunk ^ (row & 7);
            GL2LDS(A + (size_t)(m0 + row) * K + k0 + g * 8, &As[r0 * 64]);
        }
#pragma unroll
        for (int c = 0; c < BN / 32; ++c) {  // B: BN rows
            const int r0 = wv * (BN / 4) + c * 8;
            const int row = r0 + lrow;
            const int g = lchunk ^ (row & 7);
            GL2LDS(Bt + (size_t)(n0 + row) * K + k0 + g * 8, &Bs[r0 * 64]);
        }
        __syncthreads();  // drains global_load_lds (vmcnt) + protects prior reads
#pragma unroll
        for (int ks = 0; ks < 2; ++ks) {
            const int p = ((ks << 2) | quad) ^ (l15 & 7);
            bf16x8 af[4], bfr[NBW];
#pragma unroll
            for (int i = 0; i < 4; ++i)
                af[i] = *(const bf16x8*)&As[(wm + i * 16 + l15) * 64 + p * 8];
#pragma unroll
            for (int j = 0; j < NBW; ++j)
                bfr[j] = *(const bf16x8*)&Bs[(wn + j * 16 + l15) * 64 + p * 8];
#pragma unroll
            for (int mb = 0; mb < 4; ++mb)
#pragma unroll
                for (int nb = 0; nb < NBW; ++nb)
                    acc[mb][nb] = __builtin_amdgcn_mfma_f32_16x16x32_bf16(af[mb], bfr[nb],
                                                                          acc[mb][nb], 0, 0, 0);
        }
        __syncthreads();  // protect LDS before next stage overwrites
    }
    // epilogue: C/D layout col=lane&15, row=(lane>>4)*4+reg
    const int rb = m0 + wm + (quad << 2);
    const int cbase = n0 + wn + l15;
#pragma unroll
    for (int mb = 0; mb < 4; ++mb)
#pragma unroll
        for (int nb = 0; nb < NBW; ++nb) {
            const int col = cbase + nb * 16;
            if (MODE == 0) {
#pragma unroll
                for (int r = 0; r < 4; ++r) {
                    const int row = rb + mb * 16 + r;
                    C[(size_t)row * N + col] = acc[mb][nb][r] + bias[col];
                }
            } else if (col < 2048) {  // Q|K: row-major bf16 [M][2048]
#pragma unroll
                for (int r = 0; r < 4; ++r) {
                    const int row = rb + mb * 16 + r;
                    Cb[(size_t)row * 2048 + col] = f2bf(acc[mb][nb][r]);
                }
            } else {  // V: permuted V^T store; lane's 4 seq rows are 4 consecutive pos
                      // seq6 = quad*4 + mb*16 + r -> a=mb>>1, b=mb&1, c=quad, d=r
                const int pos = (((mb >> 1) * 4 + quad) << 3) + ((mb & 1) << 2);
                uint2 o;
                o.x = cvtpk(acc[mb][nb][0], acc[mb][nb][1]);
                o.y = cvtpk(acc[mb][nb][2], acc[mb][nb][3]);
                *(uint2*)(Vt + (size_t)(col - 2048) * 4096 + (m0 + wm) + pos) = o;
            }
        }
}

// ---------------- MFMA flash attention v11: R5 structure + cvt_pk packing ----------------
// R5 structure is the proven optimum (186.6 us): 4-wave blocks, 3/CU, 768 grid —
// cross-block phase overlap is THE mechanism (R6's 8-wave blocks killed it, -5%).
// v11 change: P-pack via v_cvt_pk_bf16_f32 (8 insts/iter vs 24) on the exp critical
// path; same in epilogue. rall in LDS (lgkm domain — R2 lesson); no rv preload and
// no launch_bounds tightening (R4 spill lesson).
// qkb: bf16 [4096][2048] (Q|K).  vtb: bf16 [1024][4096] permuted.  rtab fp32 [16][2048].
__global__ __launch_bounds__(256, 3) void attn_kernel(const u16* __restrict__ qkb,
                                                      const u16* __restrict__ vtb,
                                                      const float* __restrict__ rtab,
                                                      u16* __restrict__ ctxb,
                                                      u32* __restrict__ counter) {
    __shared__ __align__(16) u16 Kt[2][4096];   // [kseq][d] swizzled, 8KB x2
    __shared__ __align__(16) u16 Vt2[2][4096];  // [d][kseq-permuted] swizzled, 8KB x2
    __shared__ __align__(16) float rall[2048];  // R_hat*log2e/8 row for this head
    __shared__ int jobS;

    const int t = threadIdx.x, lane = t & 63, wv = t >> 6;
    const int l15 = lane & 15, quad = lane >> 4;
    const int lrow = lane >> 3, lchunk = lane & 7;
    const int half0 = (wv & 1) * 32;

    for (;;) {
        if (t == 0) jobS = (int)atomicAdd(counter, 1u);
        __syncthreads();       // jobS visible; fences prior job's LDS reads
        const int job = jobS;
        if (job >= 1024) break;
        const int qt = 31 - (job >> 5);       // longest jobs first
        const int bh = job & 31;
        const int b = bh >> 4, h = bh & 15;
        const int q0 = qt << 6;

        // rall fill, vectorized f32x4 (q0+64 is a multiple of 64 -> exact)
        {
            const float4* src = (const float4*)(rtab + (h << 11));
            const int nf = (q0 + 64) >> 2;
            for (int i = t; i < nf; i += 256) ((float4*)rall)[i] = src[i];
        }

        // Q as B-operand fragments for S^T: lane n=l15 -> q = q0+wv*16+l15, k=d
        bf16x8 qb[2];
        {
            const u16* qrow = qkb + (size_t)(b * 2048 + q0 + (wv << 4) + l15) * 2048 +
                              (h << 6) + quad * 8;
            qb[0] = *(const bf16x8*)(qrow);
            qb[1] = *(const bf16x8*)(qrow + 32);
        }

        f32x4 cacc[4];   // ctx^T accum: db d-blocks, lane holds (d=quad*4+r, q=l15)
#pragma unroll
        for (int i = 0; i < 4; ++i) cacc[i] = (f32x4){0.f, 0.f, 0.f, 0.f};
        f32x4 lacc4 = (f32x4){0.f, 0.f, 0.f, 0.f};  // 4-chain softmax denom partials

        // stage kt=0 into buffer 0 (waves 0,1: K; waves 2,3: V^T)
#pragma unroll
        for (int c = 0; c < 4; ++c) {
            const int r0 = half0 + c * 8;
            const int row = r0 + lrow;
            const int g = lchunk ^ (row & 7);
            if (wv < 2)
                GL2LDS(qkb + (size_t)(b * 2048 + row) * 2048 + 1024 + (h << 6) + g * 8,
                       &Kt[0][r0 * 64]);
            else
                GL2LDS(vtb + (size_t)((h << 6) + row) * 4096 + b * 2048 + g * 8,
                       &Vt2[0][r0 * 64]);
        }

        for (int kt = 0; kt <= qt; ++kt) {
            const int bsel = kt & 1;
            __syncthreads();  // drains staging of buf[bsel] (vmcnt) + orders LDS reuse
            if (kt < qt) {    // prefetch kt+1 into other buffer
                const int kg0 = (kt + 1) << 6;
#pragma unroll
                for (int c = 0; c < 4; ++c) {
                    const int r0 = half0 + c * 8;
                    const int row = r0 + lrow;
                    const int g = lchunk ^ (row & 7);
                    if (wv < 2)
                        GL2LDS(qkb + (size_t)(b * 2048 + kg0 + row) * 2048 + 1024 + (h << 6) + g * 8,
                               &Kt[bsel ^ 1][r0 * 64]);
                    else
                        GL2LDS(vtb + (size_t)((h << 6) + row) * 4096 + b * 2048 + kg0 + g * 8,
                               &Vt2[bsel ^ 1][r0 * 64]);
                }
            }

            // ---- S^T = K @ Q^T : 64 kseq x 16 q per wave (8 MFMA), A=K from LDS ----
            f32x4 sacc[4];
#pragma unroll
            for (int i = 0; i < 4; ++i) sacc[i] = (f32x4){0.f, 0.f, 0.f, 0.f};
            __builtin_amdgcn_s_setprio(1);
#pragma unroll
            for (int ks = 0; ks < 2; ++ks) {
                const int p = ((ks << 2) | quad) ^ (l15 & 7);
#pragma unroll
                for (int mb = 0; mb < 4; ++mb) {
                    bf16x8 ka = *(const bf16x8*)&Kt[bsel][(mb * 16 + l15) * 64 + p * 8];
                    sacc[mb] = __builtin_amdgcn_mfma_f32_16x16x32_bf16(ka, qb[ks],
                                                                       sacc[mb], 0, 0, 0);
                }
            }
            __builtin_amdgcn_s_setprio(0);

            // ---- gate + exp2 (fixed m=0), 4-chain l accum, cvt_pk P to bf16 regs ----
            // lane value (mb,r): q = q0+wv*16+l15, kseq = kg0+mb*16+quad*4+r
            const int D0 = q0 - (kt << 6) + (wv << 4) + l15;  // q - kg0 - local kseq base
            u32 pk[4][2];
            if (kt < qt) {  // off-diagonal: dist >= 1 guaranteed
#pragma unroll
                for (int mb = 0; mb < 4; ++mb) {
                    float pe[4];
#pragma unroll
                    for (int r = 0; r < 4; ++r) {
                        const int dist = D0 - (mb * 16 + (quad << 2) + r);
                        pe[r] = exp2f(fmaxf(sacc[mb][r], 0.f) * rall[dist]);
                        lacc4[r] += pe[r];
                    }
                    pk[mb][0] = cvtpk(pe[0], pe[1]);
                    pk[mb][1] = cvtpk(pe[2], pe[3]);
                }
            } else {  // diagonal tile: causal mask (dist<0 -> 0)
#pragma unroll
                for (int mb = 0; mb < 4; ++mb) {
                    float pe[4];
#pragma unroll
                    for (int r = 0; r < 4; ++r) {
                        const int dist = D0 - (mb * 16 + (quad << 2) + r);
                        const int di = dist < 0 ? 0 : dist;
                        float p0 = exp2f(fmaxf(sacc[mb][r], 0.f) * rall[di]);
                        pe[r] = (dist < 0) ? 0.f : p0;
                        lacc4[r] += pe[r];
                    }
                    pk[mb][0] = cvtpk(pe[0], pe[1]);
                    pk[mb][1] = cvtpk(pe[2], pe[3]);
                }
            }

            // ---- ctx^T += V^T @ P^T : 8 MFMA, B-frag = own packed P regs ----
            // permuted Vt2: A-frag for (ks,db) is ONE b128 at chunk (4ks+quad)^swz
            __builtin_amdgcn_s_setprio(1);
#pragma unroll
            for (int ks = 0; ks < 2; ++ks) {
                int4 pv = {(int)pk[2 * ks][0], (int)pk[2 * ks][1],
                           (int)pk[2 * ks + 1][0], (int)pk[2 * ks + 1][1]};
                bf16x8 pb = *(bf16x8*)&pv;
                const int g = (4 * ks + quad) ^ (l15 & 7);
#pragma unroll
                for (int db = 0; db < 4; ++db) {
                    bf16x8 vf = *(const bf16x8*)&Vt2[bsel][(db * 16 + l15) * 64 + g * 8];
                    cacc[db] = __builtin_amdgcn_mfma_f32_16x16x32_bf16(vf, pb,
                                                                       cacc[db], 0, 0, 0);
                }
            }
            __builtin_amdgcn_s_setprio(0);
        }

        // ---- epilogue: l = quad-column reduce; normalize; store ctx (8B/store) ----
        float lt = (lacc4[0] + lacc4[1]) + (lacc4[2] + lacc4[3]);
        lt += __shfl_xor(lt, 16, 64);
        lt += __shfl_xor(lt, 32, 64);
        const float inv = 1.f / lt;
        u16* op = ctxb + (size_t)(b * 2048 + q0 + (wv << 4) + l15) * 1024 +
                  (h << 6) + (quad << 2);
#pragma unroll
        for (int db = 0; db < 4; ++db) {
            uint2 o;
            o.x = cvtpk(cacc[db][0] * inv, cacc[db][1] * inv);
            o.y = cvtpk(cacc[db][2] * inv, cacc[db][3] * inv);
            *(uint2*)(op + db * 16) = o;
        }
        // loop-top __syncthreads() fences these LDS reads before next job's writes
    }
}

extern "C" void kernel_launch(void* const* d_in, const int* in_sizes, int n_in,
                              void* d_out, int out_size, void* d_ws, size_t ws_size,
                              hipStream_t stream) {
    const float* x  = (const float*)d_in[0];
    const float* Wq = (const float*)d_in[1];
    const float* Wk = (const float*)d_in[2];
    const float* Wv = (const float*)d_in[3];
    const float* Wo = (const float*)d_in[4];
    const float* bo = (const float*)d_in[5];
    const float* w  = (const float*)d_in[6];
    const float* v  = (const float*)d_in[7];
    float* out = (float*)d_out;

    char* w8 = (char*)d_ws;
    u16*  xb   = (u16*)(w8);                     //  8 MB : x bf16 [4096][1024]
    u16*  Wcat = (u16*)(w8 + (8u << 20));        //  6 MB : (Wq|Wk|Wv)^T bf16 [3072][1024]
    u16*  Wot  = (u16*)(w8 + (14u << 20));       //  2 MB : Wo^T bf16 [1024][1024]
    u16*  qkb  = (u16*)(w8 + (16u << 20));       // 16 MB : Q|K bf16 [4096][2048]
    u16*  vtb  = (u16*)(w8 + (32u << 20));       //  8 MB : V^T bf16 [1024][4096] (permuted)
    u16*  ctxb = (u16*)(w8 + (40u << 20));       //  8 MB : ctx bf16 [4096][1024]
    float* rtab = (float*)(w8 + (48u << 20));    // 128 KB: R_hat*log2e/8 [16][2048]
    u32*  counter = (u32*)(w8 + (48u << 20) + (1u << 17));  // 4 B : job counter

    // fused prep: cast (4096 blk) | weight transpose (4096 blk) | rtab+counter (128 blk)
    prep_kernel<<<8320, 256, 0, stream>>>(x, Wq, Wk, Wv, Wo, w, v, xb, Wcat, Wot, rtab,
                                          counter);
    // QKV fused projection -> bf16 qkb (Q|K) + V^T direct (permuted)  [M=4096, N=3072, K=1024]
    gemm128<1, 128><<<dim3(24, 32), 256, 0, stream>>>(xb, Wcat, nullptr, nullptr, qkb, vtb,
                                                      4096, 3072, 1024);
    // MFMA flash attention: 768 persistent blocks (3/CU), work-stealing
    attn_kernel<<<768, 256, 0, stream>>>(qkb, vtb, rtab, ctxb, counter);
    // output projection + bias (fp32 out)   [M=4096, N=1024, K=1024], 128x64 tiles
    gemm128<0, 64><<<dim3(16, 32), 256, 0, stream>>>(ctxb, Wot, out, bo, nullptr, nullptr,
                                                     4096, 1024, 1024);
}